// Round 1
// baseline (91.710 us; speedup 1.0000x reference)
//
#include <hip/hip_runtime.h>

#define NP 16384
#define NS 8192
#define DP 256
#define DS 128
#define DI 128

// workspace layout (float offsets)
#define WSUM_P 0                    // 256
#define WSUM_S 256                  // 128
#define BSUMS  384                  // [0]=bsum_p [1]=bsum_s
#define R_P    512                  // NP
#define R_S    (R_P + NP)           // NS
#define STATS  (R_S + NS)           // Mp, Zp, Ms, Zs
#define PART_P 25600                // 256*DP
#define PART_S (PART_P + 256*DP)    // 64*DS
#define U_P    (PART_S + 64*DS)     // DP
#define U_S    (U_P + DP)           // DS

// output layout (float offsets)
#define O1 (NP*DP)                  // start of prot_idx region
#define O2 (O1 + NP)                // start of sub_out region
#define O3 (O2 + NS*DS)             // start of sub_idx region

// K0: column-sums of projection weights + bias sums (tiny, 1 block)
__global__ void k0_wsums(const float* __restrict__ Wpp, const float* __restrict__ bpp,
                         const float* __restrict__ Wsp, const float* __restrict__ bsp,
                         float* __restrict__ ws) {
    int t = threadIdx.x;
    {   // wsum_p[c] = sum_d Wpp[c*DI+d], c in [0,256)
        float s = 0.f;
        const float* row = Wpp + t * DI;
        for (int d = 0; d < DI; ++d) s += row[d];
        ws[WSUM_P + t] = s;
    }
    if (t < DS) {
        float s = 0.f;
        const float* row = Wsp + t * DI;
        for (int d = 0; d < DI; ++d) s += row[d];
        ws[WSUM_S + t] = s;
    }
    if (t == 0) {
        float s = 0.f;
        for (int d = 0; d < DI; ++d) s += bpp[d];
        ws[BSUMS + 0] = s;
        s = 0.f;
        for (int d = 0; d < DI; ++d) s += bsp[d];
        ws[BSUMS + 1] = s;
    }
}

// K1: r_p[i] = prot_node[i]·wsum_p + bsum_p ; r_s[j] = sub_node[j]·wsum_s + bsum_s
// one wave per row
__global__ void k1_rowsum(const float* __restrict__ pn, const float* __restrict__ sn,
                          float* __restrict__ ws) {
    int wid  = (blockIdx.x * blockDim.x + threadIdx.x) >> 6;
    int lane = threadIdx.x & 63;
    if (wid < NP) {
        const float4 x = *(const float4*)(pn + (size_t)wid * DP + lane * 4);
        const float4 w = *(const float4*)(ws + WSUM_P + lane * 4);
        float s = x.x * w.x + x.y * w.y + x.z * w.z + x.w * w.w;
        for (int m = 32; m >= 1; m >>= 1) s += __shfl_xor(s, m, 64);
        if (lane == 0) ws[R_P + wid] = s + ws[BSUMS + 0];
    } else {
        int row = wid - NP;
        if (row < NS) {
            const float2 x = *(const float2*)(sn + (size_t)row * DS + lane * 2);
            const float2 w = *(const float2*)(ws + WSUM_S + lane * 2);
            float s = x.x * w.x + x.y * w.y;
            for (int m = 32; m >= 1; m >>= 1) s += __shfl_xor(s, m, 64);
            if (lane == 0) ws[R_S + row] = s + ws[BSUMS + 1];
        }
    }
}

// K2: softmax stats (max, sum-of-exp) over gathered r[idx]; block 0 = prot, block 1 = sub
__global__ void k2_stats(const int* __restrict__ pidx, const int* __restrict__ sidx,
                         float* __restrict__ ws) {
    const bool isP = (blockIdx.x == 0);
    const int n = isP ? NP : NS;
    const float* r = ws + (isP ? R_P : R_S);
    const int* idx = isP ? pidx : sidx;
    __shared__ float red[1024];
    int t = threadIdx.x;
    float mx = -INFINITY;
    for (int i = t; i < n; i += 1024) mx = fmaxf(mx, r[idx[i]]);
    red[t] = mx; __syncthreads();
    for (int s = 512; s > 0; s >>= 1) {
        if (t < s) red[t] = fmaxf(red[t], red[t + s]);
        __syncthreads();
    }
    float M = red[0];
    __syncthreads();
    float sum = 0.f;
    for (int i = t; i < n; i += 1024) sum += expf(r[idx[i]] - M);
    red[t] = sum; __syncthreads();
    for (int s = 512; s > 0; s >>= 1) {
        if (t < s) red[t] += red[t + s];
        __syncthreads();
    }
    if (t == 0) { ws[STATS + (isP ? 0 : 2)] = M; ws[STATS + (isP ? 1 : 3)] = red[0]; }
}

// K3: per-block partial weighted column sums of node features.
// blocks [0,256): prot (64 rows each); blocks [256,320): sub (128 rows each)
__global__ void k3_partial(const float* __restrict__ pn, const float* __restrict__ sn,
                           const int* __restrict__ pidx, const int* __restrict__ sidx,
                           float* __restrict__ ws) {
    __shared__ float sh[384];
    int b = blockIdx.x;
    int t = threadIdx.x;
    if (b < 256) {
        const float Mp = ws[STATS + 0];
        int base = b * 64;
        if (t < 64) sh[t] = expf(ws[R_P + pidx[base + t]] - Mp);
        __syncthreads();
        float acc = 0.f;
        const float* rowp = pn + (size_t)base * DP + t;
        for (int k = 0; k < 64; ++k) acc += sh[k] * rowp[(size_t)k * DP];
        ws[PART_P + b * DP + t] = acc;
    } else {
        const float Ms = ws[STATS + 2];
        int bs = b - 256;
        int base = bs * 128;
        if (t < 128) sh[t] = expf(ws[R_S + sidx[base + t]] - Ms);
        __syncthreads();
        int c = t & 127, par = t >> 7;
        float acc = 0.f;
        for (int k = par; k < 128; k += 2) acc += sh[k] * sn[(size_t)(base + k) * DS + c];
        sh[128 + t] = acc;
        __syncthreads();
        if (t < 128) ws[PART_S + bs * DS + t] = sh[128 + t] + sh[256 + t];
    }
}

// K4: reduce partials -> m; tiny matvecs m -> v -> u (1 block, 256 threads)
__global__ void k4_small(const float* __restrict__ Wpp, const float* __restrict__ bpp,
                         const float* __restrict__ Wsp, const float* __restrict__ bsp,
                         const float* __restrict__ Wpo, const float* __restrict__ bpo,
                         const float* __restrict__ Wso, const float* __restrict__ bso,
                         float* __restrict__ ws) {
    __shared__ float m_p[DP], m_s[DS], v_p[DI], v_s[DI];
    int t = threadIdx.x;
    float invZp = 1.f / ws[STATS + 1];
    float invZs = 1.f / ws[STATS + 3];
    {
        float s = 0.f;
        for (int b = 0; b < 256; ++b) s += ws[PART_P + b * DP + t];
        m_p[t] = s * invZp;
    }
    if (t < DS) {
        float s = 0.f;
        for (int b = 0; b < 64; ++b) s += ws[PART_S + b * DS + t];
        m_s[t] = s * invZs;
    }
    __syncthreads();
    if (t < DI) {
        float s = bpp[t];
        for (int c = 0; c < DP; ++c) s += m_p[c] * Wpp[c * DI + t];
        v_p[t] = s;
        float s2 = bsp[t];
        for (int c = 0; c < DS; ++c) s2 += m_s[c] * Wsp[c * DI + t];
        v_s[t] = s2;
    }
    __syncthreads();
    {   // u_p[c] = v_s · Wpo[:,c] + bpo[c]
        float s = bpo[t];
        for (int d = 0; d < DI; ++d) s += v_s[d] * Wpo[d * DP + t];
        ws[U_P + t] = s;
    }
    if (t < DS) {   // u_s[c] = v_p · Wso[:,c] + bso[c]
        float s = bso[t];
        for (int d = 0; d < DI; ++d) s += v_p[d] * Wso[d * DS + t];
        ws[U_S + t] = s;
    }
}

// K5: finalize all four outputs, float4 grid-stride
__global__ void k5_final(const float* __restrict__ pn, const float* __restrict__ sn,
                         const int* __restrict__ pidx, const int* __restrict__ sidx,
                         const float* __restrict__ ws, float* __restrict__ out,
                         int total) {
    __shared__ float up[DP];
    __shared__ float us[DS];
    int t = threadIdx.x;
    up[t] = ws[U_P + t];
    if (t < DS) us[t] = ws[U_S + t];
    __syncthreads();
    int total4 = total >> 2;
    for (int g = blockIdx.x * blockDim.x + t; g < total4; g += gridDim.x * blockDim.x) {
        int e = g * 4;
        float4 o;
        if (e < O1) {
            float4 x = *(const float4*)(pn + e);
            int c = e & (DP - 1);
            o = make_float4(x.x + up[c], x.y + up[c + 1], x.z + up[c + 2], x.w + up[c + 3]);
        } else if (e < O2) {
            int i = e - O1;
            int4 v = *(const int4*)(pidx + i);
            o = make_float4((float)v.x, (float)v.y, (float)v.z, (float)v.w);
        } else if (e < O3) {
            int i = e - O2;
            float4 x = *(const float4*)(sn + i);
            int c = i & (DS - 1);
            o = make_float4(x.x + us[c], x.y + us[c + 1], x.z + us[c + 2], x.w + us[c + 3]);
        } else {
            int i = e - O3;
            int4 v = *(const int4*)(sidx + i);
            o = make_float4((float)v.x, (float)v.y, (float)v.z, (float)v.w);
        }
        *(float4*)(out + e) = o;
    }
}

extern "C" void kernel_launch(void* const* d_in, const int* in_sizes, int n_in,
                              void* d_out, int out_size, void* d_ws, size_t ws_size,
                              hipStream_t stream) {
    const float* pn  = (const float*)d_in[0];
    const float* sn  = (const float*)d_in[1];
    const float* Wpp = (const float*)d_in[2];
    const float* bpp = (const float*)d_in[3];
    const float* Wsp = (const float*)d_in[4];
    const float* bsp = (const float*)d_in[5];
    const float* Wpo = (const float*)d_in[6];
    const float* bpo = (const float*)d_in[7];
    const float* Wso = (const float*)d_in[8];
    const float* bso = (const float*)d_in[9];
    const int* pidx  = (const int*)d_in[10];
    const int* sidx  = (const int*)d_in[11];
    float* ws  = (float*)d_ws;
    float* out = (float*)d_out;

    hipLaunchKernelGGL(k0_wsums, dim3(1), dim3(256), 0, stream, Wpp, bpp, Wsp, bsp, ws);
    hipLaunchKernelGGL(k1_rowsum, dim3((NP + NS) / 4), dim3(256), 0, stream, pn, sn, ws);
    hipLaunchKernelGGL(k2_stats, dim3(2), dim3(1024), 0, stream, pidx, sidx, ws);
    hipLaunchKernelGGL(k3_partial, dim3(320), dim3(256), 0, stream, pn, sn, pidx, sidx, ws);
    hipLaunchKernelGGL(k4_small, dim3(1), dim3(256), 0, stream,
                       Wpp, bpp, Wsp, bsp, Wpo, bpo, Wso, bso, ws);
    hipLaunchKernelGGL(k5_final, dim3(2048), dim3(256), 0, stream,
                       pn, sn, pidx, sidx, ws, out, out_size);
}